// Round 5
// baseline (273.619 us; speedup 1.0000x reference)
//
#include <hip/hip_runtime.h>

#define IRR    56
#define EF     48
#define WN     832
#define NEDGE  160000
#define NNODE  8000
#define TE     16          // edges per wave (= per block)
#define NT     64
#define NBLK   (NEDGE / TE)

#define SG_STRIDE 60       // floats
#define SH_STRIDE 72       // ushorts
#define SF_STRIDE 121      // floats

#define INV_SQRT3 0.5773502691896258f
#define INV_SQRT2 0.7071067811865476f
#define A_SCAL    0.22360679774997896f   // 1/sqrt(20)
#define A_VEC     0.20412414523193154f   // 1/sqrt(24)

typedef __bf16 bf16x8 __attribute__((ext_vector_type(8)));
typedef float  f32x4  __attribute__((ext_vector_type(4)));
typedef unsigned short u16x8 __attribute__((ext_vector_type(8)));
typedef unsigned short u16x4 __attribute__((ext_vector_type(4)));

__device__ __forceinline__ unsigned short f2bf(float f) {
    unsigned int u = __builtin_bit_cast(unsigned int, f);
    u += 0x7FFFu + ((u >> 16) & 1u);          // RNE
    return (unsigned short)(u >> 16);
}

// ---- setup: zero hist + build bf16 transposed weight tables [n][64] ----
__global__ void k_setup(const float* __restrict__ w1, const float* __restrict__ b1,
                        const float* __restrict__ w2, const float* __restrict__ b2,
                        unsigned short* __restrict__ W1T, unsigned short* __restrict__ W2T,
                        int* __restrict__ hist)
{
    int i = blockIdx.x * 256 + threadIdx.x;
    if (i < NNODE) hist[i] = 0;
    if (i < EF * WN) { int k = i / WN, n = i - k * WN; W2T[n * 64 + k] = f2bf(w2[i]); }
    if (i < WN * 16) { int n = i >> 4, kk = EF + (i & 15); W2T[n * 64 + kk] = (kk == EF) ? f2bf(b2[n]) : (unsigned short)0; }
    if (i < EF * EF) { int k = i / EF, n = i - k * EF; W1T[n * 64 + k] = f2bf(w1[i]); }
    if (i < EF * 16) { int n = i >> 4, kk = EF + (i & 15); W1T[n * 64 + kk] = (kk == EF) ? f2bf(b1[n]) : (unsigned short)0; }
}

__global__ void k_hist(const int* __restrict__ edge_index, int* __restrict__ hist)
{
    int e = blockIdx.x * 256 + threadIdx.x;
    if (e < NEDGE) atomicAdd(&hist[edge_index[e]], 1);
}

// single-block exclusive scan of hist[8000] -> offs, cursor
__global__ __launch_bounds__(1024) void k_scan(const int* __restrict__ hist,
                                               int* __restrict__ offs, int* __restrict__ cursor)
{
    __shared__ int lsum[1024];
    const int t = threadIdx.x;
    const int base = t * 8;
    int v[8]; int s = 0;
    #pragma unroll
    for (int j = 0; j < 8; j++) v[j] = (base + j < NNODE) ? hist[base + j] : 0;
    #pragma unroll
    for (int j = 0; j < 8; j++) { int tmp = v[j]; v[j] = s; s += tmp; }
    lsum[t] = s;
    __syncthreads();
    for (int off = 1; off < 1024; off <<= 1) {
        int add = (t >= off) ? lsum[t - off] : 0;
        __syncthreads();
        lsum[t] += add;
        __syncthreads();
    }
    int ex = lsum[t] - s;
    #pragma unroll
    for (int j = 0; j < 8; j++) {
        if (base + j < NNODE) { int o = ex + v[j]; offs[base + j] = o; cursor[base + j] = o; }
    }
}

__global__ void k_fill(const int* __restrict__ edge_index,
                       int* __restrict__ cursor, int* __restrict__ eid)
{
    int e = blockIdx.x * 256 + threadIdx.x;
    if (e < NEDGE) {
        int pos = atomicAdd(&cursor[edge_index[e]], 1);
        eid[pos] = e;
    }
}

__global__ __launch_bounds__(NT) void tp_fused(
    const float* __restrict__ node_attr,
    const float* __restrict__ edge_attr,
    const float* __restrict__ edge_sh,
    const int*   __restrict__ edge_index,
    const unsigned short* __restrict__ W1T,
    const unsigned short* __restrict__ W2T,
    unsigned short* __restrict__ tpB)
{
    __shared__ __align__(16) float sGO[TE * SG_STRIDE];          // gather tile, later sO
    __shared__ __align__(16) unsigned short sH[TE * SH_STRIDE];  // H^T staging
    __shared__ float sF[TE * SF_STRIDE];                         // TP features
    __shared__ float sS1[TE][4];
    __shared__ int   sDst[TE];

    const int lane = threadIdx.x;
    const int m    = lane & 15;
    const int quad = lane >> 4;
    const int e0   = blockIdx.x * TE;

    if (lane < TE) sDst[lane] = edge_index[NEDGE + e0 + lane];
    __syncthreads();

    // ---- gather node rows ----
    {
        const float* nrow = node_attr + (size_t)sDst[m] * IRR;
        float* g = sGO + m * SG_STRIDE;
        #pragma unroll
        for (int t = 0; t < 3; t++) {
            int c = quad + t * 4;
            *(float4*)(g + c * 4) = *(const float4*)(nrow + c * 4);
        }
        if (quad < 2) { int c = 12 + quad; *(float4*)(g + c * 4) = *(const float4*)(nrow + c * 4); }
    }

    // ---- GEMM1 transposed: lane holds H[e=m][hid] ----
    {
        const float* arow = edge_attr + (size_t)(e0 + m) * EF;
        float av0[8], av1[8];
        {
            float4 p0 = *(const float4*)(arow + quad * 8);
            float4 p1 = *(const float4*)(arow + quad * 8 + 4);
            av0[0]=p0.x; av0[1]=p0.y; av0[2]=p0.z; av0[3]=p0.w;
            av0[4]=p1.x; av0[5]=p1.y; av0[6]=p1.z; av0[7]=p1.w;
        }
        if (quad < 2) {
            float4 p0 = *(const float4*)(arow + 32 + quad * 8);
            float4 p1 = *(const float4*)(arow + 32 + quad * 8 + 4);
            av1[0]=p0.x; av1[1]=p0.y; av1[2]=p0.z; av1[3]=p0.w;
            av1[4]=p1.x; av1[5]=p1.y; av1[6]=p1.z; av1[7]=p1.w;
        } else {
            #pragma unroll
            for (int j = 0; j < 8; j++) av1[j] = 0.f;
            if (quad == 2) av1[0] = 1.f;           // bias row k=48
        }
        u16x8 ub0, ub1;
        #pragma unroll
        for (int j = 0; j < 8; j++) { ub0[j] = f2bf(av0[j]); ub1[j] = f2bf(av1[j]); }
        bf16x8 hb0 = __builtin_bit_cast(bf16x8, ub0);
        bf16x8 hb1 = __builtin_bit_cast(bf16x8, ub1);

        #pragma unroll
        for (int nth = 0; nth < 3; nth++) {
            bf16x8 a0 = __builtin_bit_cast(bf16x8, *(const u16x8*)&W1T[(nth*16 + m)*64 + quad*8]);
            bf16x8 a1 = __builtin_bit_cast(bf16x8, *(const u16x8*)&W1T[(nth*16 + m)*64 + 32 + quad*8]);
            f32x4 c = {0.f, 0.f, 0.f, 0.f};
            c = __builtin_amdgcn_mfma_f32_16x16x32_bf16(a0, hb0, c, 0, 0, 0);
            c = __builtin_amdgcn_mfma_f32_16x16x32_bf16(a1, hb1, c, 0, 0, 0);
            u16x4 hp;
            #pragma unroll
            for (int r = 0; r < 4; r++) hp[r] = f2bf(fmaxf(c[r], 0.f));
            *(u16x4*)&sH[m * SH_STRIDE + nth*16 + quad*4] = hp;
        }
        if (quad == 3) {
            u16x4 b = {0x3F80, 0, 0, 0}, z = {0, 0, 0, 0};
            *(u16x4*)&sH[m * SH_STRIDE + 48] = b;
            *(u16x4*)&sH[m * SH_STRIDE + 52] = z;
            *(u16x4*)&sH[m * SH_STRIDE + 56] = z;
            *(u16x4*)&sH[m * SH_STRIDE + 60] = z;
        }
    }
    __syncthreads();

    // ---- F features (quad0) ----
    if (quad == 0) {
        const float* x = sGO + m * SG_STRIDE;
        float4 sh4 = *(const float4*)&edge_sh[(size_t)(e0 + m) * 4];
        const float s0 = sh4.x, sx = sh4.y, sy = sh4.z, sz = sh4.w;
        float* F = sF + m * SF_STRIDE;
        const float c0S = s0 * A_SCAL;
        const float c0V = s0 * A_VEC;
        const float cD3 = INV_SQRT3 * A_SCAL;
        const float cC2 = INV_SQRT2 * A_VEC;
        #pragma unroll
        for (int u = 0; u < 16; u++) {
            float x0e = x[u], x0o = x[40 + u];
            F[u]       = x0e * c0S;
            F[20 + u]  = x0e * A_VEC;
            F[84 + u]  = x0o * A_VEC;
            F[104 + u] = x0o * c0S;
        }
        #pragma unroll
        for (int u = 0; u < 4; u++) {
            float a0 = x[16 + u*3], a1 = x[16 + u*3 + 1], a2 = x[16 + u*3 + 2]; // x1o
            float b0 = x[28 + u*3], b1 = x[28 + u*3 + 1], b2 = x[28 + u*3 + 2]; // x1e
            F[16 + u]  = (a0*sx + a1*sy + a2*sz) * cD3;
            F[100 + u] = (b0*sx + b1*sy + b2*sz) * cD3;
            F[48 + u*3 + 0] = (b1*sz - b2*sy) * cC2;
            F[48 + u*3 + 1] = (b2*sx - b0*sz) * cC2;
            F[48 + u*3 + 2] = (b0*sy - b1*sx) * cC2;
            F[60 + u*3 + 0] = (a1*sz - a2*sy) * cC2;
            F[60 + u*3 + 1] = (a2*sx - a0*sz) * cC2;
            F[60 + u*3 + 2] = (a0*sy - a1*sx) * cC2;
            F[36 + u*3 + 0] = a0 * c0V;  F[36 + u*3 + 1] = a1 * c0V;  F[36 + u*3 + 2] = a2 * c0V;
            F[72 + u*3 + 0] = b0 * c0V;  F[72 + u*3 + 1] = b1 * c0V;  F[72 + u*3 + 2] = b2 * c0V;
        }
        sS1[m][0] = sx; sS1[m][1] = sy; sS1[m][2] = sz;
    }
    __syncthreads();

    bf16x8 HB0 = __builtin_bit_cast(bf16x8, *(const u16x8*)&sH[m * SH_STRIDE + quad*8]);
    bf16x8 HB1 = __builtin_bit_cast(bf16x8, *(const u16x8*)&sH[m * SH_STRIDE + 32 + quad*8]);

    // ---- fused GEMM2 + consume, depth-2 W2 prefetch; P stays in registers ----
    float oe[4]  = {0.f,0.f,0.f,0.f};
    float oo[4]  = {0.f,0.f,0.f,0.f};
    float sA[4]  = {0.f,0.f,0.f,0.f};
    float sD[4]  = {0.f,0.f,0.f,0.f};
    float t1o[12] = {0.f,0.f,0.f,0.f,0.f,0.f,0.f,0.f,0.f,0.f,0.f,0.f};
    float t1e[12] = {0.f,0.f,0.f,0.f,0.f,0.f,0.f,0.f,0.f,0.f,0.f,0.f};

    const float* Fm = sF + m * SF_STRIDE;
    u16x8 w0a = *(const u16x8*)&W2T[(size_t)(m)*64 + quad*8];
    u16x8 w0b = *(const u16x8*)&W2T[(size_t)(m)*64 + 32 + quad*8];
    u16x8 w1a = *(const u16x8*)&W2T[(size_t)(16 + m)*64 + quad*8];
    u16x8 w1b = *(const u16x8*)&W2T[(size_t)(16 + m)*64 + 32 + quad*8];

    for (int nt = 0; nt < 52; nt++) {
        u16x8 na = w1a, nb = w1b;
        int ntn = nt + 2;
        if (ntn < 52) {
            na = *(const u16x8*)&W2T[(size_t)(ntn*16 + m)*64 + quad*8];
            nb = *(const u16x8*)&W2T[(size_t)(ntn*16 + m)*64 + 32 + quad*8];
        }
        f32x4 c = {0.f, 0.f, 0.f, 0.f};
        c = __builtin_amdgcn_mfma_f32_16x16x32_bf16(__builtin_bit_cast(bf16x8, w0a), HB0, c, 0, 0, 0);
        c = __builtin_amdgcn_mfma_f32_16x16x32_bf16(__builtin_bit_cast(bf16x8, w0b), HB1, c, 0, 0, 0);

        if (nt < 20) {
            float f = Fm[nt];
            #pragma unroll
            for (int r = 0; r < 4; r++) oe[r] += f * c[r];
        } else if (nt < 24) {
            float f = Fm[20 + (nt - 20)*4 + quad];
            #pragma unroll
            for (int r = 0; r < 4; r++) sA[r] += f * c[r];
        } else if (nt < 26) {
            int u = (nt - 24)*4 + quad;
            #pragma unroll
            for (int i = 0; i < 3; i++) {
                float f = Fm[36 + u*3 + i];
                #pragma unroll
                for (int r = 0; r < 4; r++) t1o[i*4 + r] += f * c[r];
            }
        } else if (nt < 28) {
            int j = (nt - 26)*4 + quad;
            #pragma unroll
            for (int i = 0; i < 3; i++) {
                float f = Fm[60 + j*3 + i];
                #pragma unroll
                for (int r = 0; r < 4; r++) t1e[i*4 + r] += f * c[r];
            }
        } else if (nt < 32) {
            float f = Fm[84 + (nt - 28)*4 + quad];
            #pragma unroll
            for (int r = 0; r < 4; r++) sD[r] += f * c[r];
        } else {
            float f = Fm[68 + nt];
            #pragma unroll
            for (int r = 0; r < 4; r++) oo[r] += f * c[r];
        }
        w0a = w1a; w0b = w1b; w1a = na; w1b = nb;
    }

    // ---- cross-quad butterfly ----
    #pragma unroll
    for (int r = 0; r < 4; r++) {
        sA[r] += __shfl_xor(sA[r], 16, 64);  sA[r] += __shfl_xor(sA[r], 32, 64);
        sD[r] += __shfl_xor(sD[r], 16, 64);  sD[r] += __shfl_xor(sD[r], 32, 64);
    }
    #pragma unroll
    for (int i = 0; i < 12; i++) {
        t1o[i] += __shfl_xor(t1o[i], 16, 64);  t1o[i] += __shfl_xor(t1o[i], 32, 64);
        t1e[i] += __shfl_xor(t1e[i], 16, 64);  t1e[i] += __shfl_xor(t1e[i], 32, 64);
    }

    // ---- write per-edge outputs to sO ----
    float* sO = sGO;
    {
        float4 v0; v0.x = oe[0]; v0.y = oe[1]; v0.z = oe[2]; v0.w = oe[3];
        float4 v1; v1.x = oo[0]; v1.y = oo[1]; v1.z = oo[2]; v1.w = oo[3];
        *(float4*)&sO[m * SG_STRIDE + quad*4]      = v0;
        *(float4*)&sO[m * SG_STRIDE + 40 + quad*4] = v1;
    }
    if (quad == 0) {
        float s1x = sS1[m][0], s1y = sS1[m][1], s1z = sS1[m][2];
        #pragma unroll
        for (int r = 0; r < 4; r++) {
            sO[m * SG_STRIDE + 16 + r*3 + 0] = sA[r] * s1x + t1o[0*4 + r];
            sO[m * SG_STRIDE + 16 + r*3 + 1] = sA[r] * s1y + t1o[1*4 + r];
            sO[m * SG_STRIDE + 16 + r*3 + 2] = sA[r] * s1z + t1o[2*4 + r];
        }
    } else if (quad == 1) {
        float s1x = sS1[m][0], s1y = sS1[m][1], s1z = sS1[m][2];
        #pragma unroll
        for (int r = 0; r < 4; r++) {
            sO[m * SG_STRIDE + 28 + r*3 + 0] = sD[r] * s1x + t1e[0*4 + r];
            sO[m * SG_STRIDE + 28 + r*3 + 1] = sD[r] * s1y + t1e[1*4 + r];
            sO[m * SG_STRIDE + 28 + r*3 + 2] = sD[r] * s1z + t1e[2*4 + r];
        }
    }
    __syncthreads();

    // ---- plain coalesced bf16 row stores (NO atomics) ----
    unsigned* tp32 = (unsigned*)tpB;
    #pragma unroll
    for (int it = 0; it < 7; it++) {
        int idx = it * 64 + lane;          // 0..447 ; 28 dwords per edge
        int e = idx / 28, chp = idx - e * 28;
        float lo = sO[e * SG_STRIDE + chp*2];
        float hi = sO[e * SG_STRIDE + chp*2 + 1];
        unsigned pk = ((unsigned)f2bf(hi) << 16) | (unsigned)f2bf(lo);
        tp32[(size_t)(e0 + e) * 28 + chp] = pk;
    }
}

// ---- per-node gather-reduce + divide: one wave per node ----
__global__ __launch_bounds__(256) void k_reduce(
    const unsigned short* __restrict__ tpB,
    const int* __restrict__ hist, const int* __restrict__ offs,
    const int* __restrict__ eid, float* __restrict__ out)
{
    const int lane = threadIdx.x & 63;
    const int wv   = threadIdx.x >> 6;
    const int n    = blockIdx.x * 4 + wv;   // grid = 2000 blocks -> 8000 nodes exactly

    const int cnt = hist[n];
    const int beg = offs[n];
    const unsigned* tp32 = (const unsigned*)tpB;

    if (lane < 28) {
        float ax = 0.f, ay = 0.f;
        unsigned cur = 0;
        if (cnt > 0) {
            int e = eid[beg];
            cur = tp32[(size_t)e * 28 + lane];
        }
        for (int i = 0; i < cnt; i++) {
            unsigned nxt = 0;
            if (i + 1 < cnt) {
                int en = eid[beg + i + 1];
                nxt = tp32[(size_t)en * 28 + lane];
            }
            ax += __builtin_bit_cast(float, cur << 16);
            ay += __builtin_bit_cast(float, cur & 0xFFFF0000u);
            cur = nxt;
        }
        float inv = 1.f / fmaxf((float)cnt, 1.f);
        float2 o; o.x = ax * inv; o.y = ay * inv;
        *(float2*)&out[(size_t)n * IRR + lane * 2] = o;
    }
}

extern "C" void kernel_launch(void* const* d_in, const int* in_sizes, int n_in,
                              void* d_out, int out_size, void* d_ws, size_t ws_size,
                              hipStream_t stream) {
    const float* node_attr  = (const float*)d_in[0];
    const float* edge_attr  = (const float*)d_in[1];
    const float* edge_sh    = (const float*)d_in[2];
    const float* fc_w1      = (const float*)d_in[3];
    const float* fc_b1      = (const float*)d_in[4];
    const float* fc_w2      = (const float*)d_in[5];
    const float* fc_b2      = (const float*)d_in[6];
    const int*   edge_index = (const int*)d_in[7];

    int* hist   = (int*)d_ws;                       // 8000
    int* offs   = hist + NNODE;                     // 8000
    int* cursor = offs + NNODE;                     // 8000
    int* eid    = cursor + NNODE;                   // 160000
    unsigned short* W1T = (unsigned short*)(eid + NEDGE);     // 48*64
    unsigned short* W2T = W1T + 48 * 64;                      // 832*64
    unsigned short* tpB = W2T + (size_t)WN * 64;              // 160000*56 bf16

    k_setup<<<(EF * WN + WN * 16 + 255) / 256, 256, 0, stream>>>(
        fc_w1, fc_b1, fc_w2, fc_b2, W1T, W2T, hist);
    k_hist<<<NEDGE / 256, 256, 0, stream>>>(edge_index, hist);
    k_scan<<<1, 1024, 0, stream>>>(hist, offs, cursor);
    k_fill<<<NEDGE / 256, 256, 0, stream>>>(edge_index, cursor, eid);

    tp_fused<<<NBLK, NT, 0, stream>>>(node_attr, edge_attr, edge_sh, edge_index,
                                      W1T, W2T, tpB);

    k_reduce<<<NNODE / 4, 256, 0, stream>>>(tpB, hist, offs, eid, (float*)d_out);
}